// Round 6
// baseline (240.989 us; speedup 1.0000x reference)
//
#include <hip/hip_runtime.h>
#include <stdint.h>

typedef unsigned short u16;
typedef __attribute__((ext_vector_type(4))) float floatx4;
typedef __attribute__((ext_vector_type(8))) short bf16x8;

#define MTOK   32768   // 512 windows * 64 tokens
#define KDIM   512
#define NQKV   1536
#define NWIN   512
#define N_HEAD 16
#define SECSZ  (512 * 16 * 2048)   // u16 elems per Q/K/V section (32 MB)
#define QK_SCALE 0.17677669529663687f  // 32^-0.5

__device__ __forceinline__ u16 f2bf(float f) {
  union { float f; unsigned u; } v; v.f = f;
  unsigned r = v.u + 0x7fffu + ((v.u >> 16) & 1u);
  return (u16)(r >> 16);
}

__device__ __forceinline__ void load_lds16(const void* g, void* l) {
  __builtin_amdgcn_global_load_lds((const __attribute__((address_space(1))) void*)g,
                                   (__attribute__((address_space(3))) void*)l,
                                   16, 0, 0);
}

// ---------------- kernel 1: weight convert + bias/mask table gen (x-convert is
// now pipelined INTO gemm's A-staging; the 32 MB A buffer and its 96 MB of HBM
// traffic are gone).
__global__ __launch_bounds__(256) void convert_w_tbl(const float* __restrict__ wsrc,
                                                     const float* __restrict__ btab,
                                                     u16* __restrict__ Wb,
                                                     float* __restrict__ tbl) {
  int b = blockIdx.x;
  if (b < 768) {
    int e = (b * 256 + threadIdx.x) * 4;
    const float4 v = *(const float4*)(wsrc + e);
    ushort4 o;
    o.x = f2bf(v.x); o.y = f2bf(v.y); o.z = f2bf(v.z); o.w = f2bf(v.w);
    *(ushort4*)(Wb + e) = o;
  } else {
    int q = b - 768;                   // [0,64): cls*16 + head
    int cls = q >> 4, hh = q & 15;
    int ey = cls >> 1, ex = cls & 1;   // edge flags: wy==7 / wx==7
    float* To = tbl + (q << 12);
#pragma unroll
    for (int e = 0; e < 16; ++e) {
      int idx = e * 256 + threadIdx.x;
      int i = idx >> 6, j = idx & 63;
      int ty = i >> 3, tx = i & 7, sy = j >> 3, sx = j & 7;
      int ry = ey ? (ty < 4 ? 1 : 2) : 0;
      int rx = ex ? (tx < 4 ? 1 : 2) : 0;
      int qy = ey ? (sy < 4 ? 1 : 2) : 0;
      int qx = ex ? (sx < 4 ? 1 : 2) : 0;
      float v = btab[((ty - sy + 7) * 15 + (tx - sx + 7)) * 16 + hh];
      if (ry * 3 + rx != qy * 3 + qx) v -= 100.0f;
      To[idx] = v;
    }
  }
}

// ---------------- kernel 2: QKV GEMM — R0 structure (128x128 tile, BK=32,
// 4 blocks/CU, single 3072-block launch: the R5 quarter-split cost ~10 us in
// fill/tail effects and is reverted). NEW vs R0: A comes straight from x (fp32)
// via a PIPELINED reg-stage — the x-loads for step kb+32 are issued in kb's
// COMPUTE phase (HBM latency hides under the MFMAs + barrier; drained by the
// next top-of-loop __syncthreads), and only convert+ds_write sits in the stage
// phase, overlapping the B-DMA drain. LDS dest = lAb + tid*16 == the DMA's
// layout, so frag reads / MFMA / epilogue are byte-identical to R0.
// (R3's failure mode — load+convert+write all serial inside the stage phase —
// is what this fixes.)
__global__ __launch_bounds__(256, 4) void gemm_qkv(const float* __restrict__ x,
                                                   const u16* __restrict__ Wb,
                                                   const float* __restrict__ bias,
                                                   u16* __restrict__ QKV) {
  __shared__ __attribute__((aligned(16))) char smem[18432];
  u16* Ct = (u16*)smem;

  int b = blockIdx.x;
  int xcd = b & 7, slot = b >> 3;
  int mtile = (slot / 12) * 8 + xcd;   // [0,256)
  int ntile = slot % 12;               // [0,12)

  int tid = threadIdx.x;
  int wv = tid >> 6, lane = tid & 63;
  int il = lane & 15, ch = lane >> 4;
  int wm = (wv & 1) * 64, wn = (wv >> 1) * 64;

  floatx4 acc[4][4];
  floatx4 zacc = {0.f, 0.f, 0.f, 0.f};
#pragma unroll
  for (int m = 0; m < 4; ++m)
#pragma unroll
    for (int n = 0; n < 4; ++n) acc[m][n] = zacc;

  int row0 = tid >> 2;
  int ch4 = (tid & 3) ^ (row0 & 3);    // staging swizzle (R0 form)
  // A source: window-ordered token -> x address (R3-verified math)
  int T0 = mtile * 128 + row0;         // token for A0 half (window mtile*2)
  int T1 = T0 + 64;                    // token for A1 half (window mtile*2+1)
  int w0 = T0 >> 6, t0 = T0 & 63;
  int w1 = T1 >> 6, t1 = T1 & 63;
  const float* px0 = x + ((((w0 >> 6) * 64 + ((w0 >> 3) & 7) * 8 + (t0 >> 3)) * 64
                           + (w0 & 7) * 8 + (t0 & 7)) * 512 + ch4 * 8);
  const float* px1 = x + ((((w1 >> 6) * 64 + ((w1 >> 3) & 7) * 8 + (t1 >> 3)) * 64
                           + (w1 & 7) * 8 + (t1 & 7)) * 512 + ch4 * 8);

  const u16* Bbase = Wb + (ntile * 128 + row0) * KDIM + ch4 * 8;
  char* lAb = smem;
  char* lBb = smem + 8192;
  char* lB0 = lBb + wv * 1024;
  char* lB1 = lBb + 4096 + wv * 1024;

#define STAGE_A(q0, q1, q2, q3)                                        \
  {                                                                    \
    bf16x8 p0, p1;                                                     \
    p0[0] = (short)f2bf(q0.x); p0[1] = (short)f2bf(q0.y);              \
    p0[2] = (short)f2bf(q0.z); p0[3] = (short)f2bf(q0.w);              \
    p0[4] = (short)f2bf(q1.x); p0[5] = (short)f2bf(q1.y);              \
    p0[6] = (short)f2bf(q1.z); p0[7] = (short)f2bf(q1.w);              \
    p1[0] = (short)f2bf(q2.x); p1[1] = (short)f2bf(q2.y);              \
    p1[2] = (short)f2bf(q2.z); p1[3] = (short)f2bf(q2.w);              \
    p1[4] = (short)f2bf(q3.x); p1[5] = (short)f2bf(q3.y);              \
    p1[6] = (short)f2bf(q3.z); p1[7] = (short)f2bf(q3.w);              \
    *(bf16x8*)(lAb + tid * 16) = p0;                                   \
    *(bf16x8*)(lAb + 4096 + tid * 16) = p1;                            \
  }

#define COMPUTE()                                                      \
  {                                                                    \
    bf16x8 af[4], bfr[4];                                              \
    _Pragma("unroll")                                                  \
    for (int mt = 0; mt < 4; ++mt)                                     \
      af[mt] = *(const bf16x8*)(lAb + (wm + mt * 16 + il) * 64 + (ch ^ sw) * 16); \
    _Pragma("unroll")                                                  \
    for (int nt = 0; nt < 4; ++nt)                                     \
      bfr[nt] = *(const bf16x8*)(lBb + (wn + nt * 16 + il) * 64 + (ch ^ sw) * 16); \
    _Pragma("unroll")                                                  \
    for (int mt = 0; mt < 4; ++mt)                                     \
      _Pragma("unroll")                                                \
      for (int nt = 0; nt < 4; ++nt)                                   \
        acc[mt][nt] = __builtin_amdgcn_mfma_f32_16x16x32_bf16(af[mt], bfr[nt], acc[mt][nt], 0, 0, 0); \
  }

  int sw = il & 3;
  // prologue: x-regs for kb=0 (buffer X)
  float4 xA0 = *(const float4*)(px0);
  float4 xA1 = *(const float4*)(px0 + 4);
  float4 xA2 = *(const float4*)(px1);
  float4 xA3 = *(const float4*)(px1 + 4);
  float4 xB0, xB1, xB2, xB3;

  for (int kb = 0; kb < KDIM; kb += 64) {
    // ---- step 1: consume buffer X (K-slice kb), prefetch buffer Y (kb+32)
    __syncthreads();                       // drains prev B-DMA readers + Y-loads
    load_lds16(Bbase + kb, lB0);
    load_lds16(Bbase + kb + 64 * KDIM, lB1);
    STAGE_A(xA0, xA1, xA2, xA3);
    __syncthreads();                       // B landed, A ds_writes visible
    xB0 = *(const float4*)(px0 + kb + 32);
    xB1 = *(const float4*)(px0 + kb + 36);
    xB2 = *(const float4*)(px1 + kb + 32);
    xB3 = *(const float4*)(px1 + kb + 36);
    COMPUTE();

    // ---- step 2: consume buffer Y (kb+32), prefetch buffer X (kb+64)
    __syncthreads();
    load_lds16(Bbase + kb + 32, lB0);
    load_lds16(Bbase + kb + 32 + 64 * KDIM, lB1);
    STAGE_A(xB0, xB1, xB2, xB3);
    __syncthreads();
    if (kb + 64 < KDIM) {
      xA0 = *(const float4*)(px0 + kb + 64);
      xA1 = *(const float4*)(px0 + kb + 68);
      xA2 = *(const float4*)(px1 + kb + 64);
      xA3 = *(const float4*)(px1 + kb + 68);
    }
    COMPUTE();
  }
#undef STAGE_A
#undef COMPUTE

  __syncthreads();   // K-loop LDS reads done before smem reuse

  // epilogue: C/D layout col=lane&15, row=(lane>>4)*4+reg
  int sec = ntile >> 2;              // 0=Q 1=K 2=V
  int h0 = (ntile & 3) * 4;          // 4 heads per block
  int gw0 = mtile * 2;               // 2 windows per block
  u16* dst = QKV + (size_t)sec * SECSZ;
  float sc = (sec == 0) ? QK_SCALE : 1.0f;

  for (int p = 0; p < 2; ++p) {      // pass p == window gw0+p (tokens p*64..p*64+63)
    if ((wv & 1) == p) {
      if (sec < 2) {
        // Ct[t_local=64][c=128], row stride 136 u16 (272B, 16*17 aligned)
#pragma unroll
        for (int nt = 0; nt < 4; ++nt) {
          float bv = bias[ntile * 128 + wn + nt * 16 + il];
          int cl = wn + nt * 16 + il;
#pragma unroll
          for (int mt = 0; mt < 4; ++mt) {
            int lr = mt * 16 + ch * 4;
#pragma unroll
            for (int r = 0; r < 4; ++r)
              Ct[(lr + r) * 136 + cl] = f2bf((acc[mt][nt][r] + bv) * sc);
          }
        }
      } else {
        // V transposed: Ct[c=128][t_local=64], row stride 72 u16 (144B, 16*9 aligned)
#pragma unroll
        for (int nt = 0; nt < 4; ++nt) {
          float bv = bias[ntile * 128 + wn + nt * 16 + il];
          int cl = wn + nt * 16 + il;
#pragma unroll
          for (int mt = 0; mt < 4; ++mt) {
            int lr = mt * 16 + ch * 4;
            ushort4 pk;
            pk.x = f2bf(acc[mt][nt][0] + bv);
            pk.y = f2bf(acc[mt][nt][1] + bv);
            pk.z = f2bf(acc[mt][nt][2] + bv);
            pk.w = f2bf(acc[mt][nt][3] + bv);
            *(ushort4*)(Ct + cl * 72 + lr) = pk;
          }
        }
      }
    }
    __syncthreads();

    if (sec < 2) {
      int tl = tid >> 2, dc = tid & 3;
#pragma unroll
      for (int hl = 0; hl < 4; ++hl) {
        uint4 v = *(const uint4*)(smem + tl * 272 + hl * 64 + dc * 16);
        *(uint4*)(dst + ((gw0 + p) * 16 + h0 + hl) * 2048 + tl * 32 + dc * 8) = v;
      }
    } else {
      int c0 = tid >> 3, tq = tid & 7;   // c0: d in [0,32), tq: t-chunk
#pragma unroll
      for (int hl = 0; hl < 4; ++hl) {
        uint4 v = *(const uint4*)(smem + (hl * 32 + c0) * 144 + tq * 16);
        *(uint4*)(dst + ((gw0 + p) * 16 + h0 + hl) * 2048 + c0 * 64 + tq * 8) = v;
      }
    }
    __syncthreads();   // buffer free for next pass's writers
  }
}

// ---------------- kernel 3: attention — R5 version, measured 40.9 us
// (one block per (window,head), 8192 blocks; barrier-free P hand-off within the
// wave; V frags hoisted above softmax). Unchanged.
__global__ __launch_bounds__(256) void attn(const u16* __restrict__ QKV,
                                            const float* __restrict__ tbl,
                                            float* __restrict__ out) {
  __shared__ __attribute__((aligned(16))) u16 Pl[64 * 88];

  int bid = blockIdx.x;
  int w = bid >> 4, h = bid & 15;
  int tid = threadIdx.x;

  int lane = tid & 63, wv = tid >> 6;
  int il = lane & 15, ch = lane >> 4;
  const u16* Qb = QKV + (w * 16 + h) * 2048;
  const u16* Kb = Qb + SECSZ;
  const u16* Vt = Qb + 2 * (size_t)SECSZ;

  bf16x8 aq = *(const bf16x8*)(Qb + (wv * 16 + il) * 32 + ch * 8);
  floatx4 zacc = {0.f, 0.f, 0.f, 0.f};
  floatx4 s[4];
#pragma unroll
  for (int jt = 0; jt < 4; ++jt) {
    bf16x8 bk = *(const bf16x8*)(Kb + (jt * 16 + il) * 32 + ch * 8);
    s[jt] = __builtin_amdgcn_mfma_f32_16x16x32_bf16(aq, bk, zacc, 0, 0, 0);
  }

  // V frags hoisted: issue now, consumed after softmax
  bf16x8 bv0[2], bv1[2];
#pragma unroll
  for (int kk = 0; kk < 2; ++kk) {
    bv0[kk] = *(const bf16x8*)(Vt + il * 64 + kk * 32 + ch * 8);
    bv1[kk] = *(const bf16x8*)(Vt + (16 + il) * 64 + kk * 32 + ch * 8);
  }

  int winidx = w & 63;
  int wy = winidx >> 3, wx = winidx & 7;
  int cls = ((wy == 7) ? 2 : 0) | ((wx == 7) ? 1 : 0);
  const float* T = tbl + (((cls << 4) | h) << 12);

  float val[4][4];
#pragma unroll
  for (int r = 0; r < 4; ++r) {
    int i = wv * 16 + ch * 4 + r;
#pragma unroll
    for (int jt = 0; jt < 4; ++jt)
      val[r][jt] = s[jt][r] + T[i * 64 + jt * 16 + il];
  }

#pragma unroll
  for (int r = 0; r < 4; ++r) {
    float m = fmaxf(fmaxf(val[r][0], val[r][1]), fmaxf(val[r][2], val[r][3]));
    m = fmaxf(m, __shfl_xor(m, 1, 64));
    m = fmaxf(m, __shfl_xor(m, 2, 64));
    m = fmaxf(m, __shfl_xor(m, 4, 64));
    m = fmaxf(m, __shfl_xor(m, 8, 64));
    float sum = 0.f;
#pragma unroll
    for (int jt = 0; jt < 4; ++jt) { val[r][jt] = __expf(val[r][jt] - m); sum += val[r][jt]; }
    sum += __shfl_xor(sum, 1, 64);
    sum += __shfl_xor(sum, 2, 64);
    sum += __shfl_xor(sum, 4, 64);
    sum += __shfl_xor(sum, 8, 64);
    float inv = 1.0f / sum;
    int i = wv * 16 + ch * 4 + r;
#pragma unroll
    for (int jt = 0; jt < 4; ++jt)
      Pl[i * 88 + jt * 16 + il] = f2bf(val[r][jt] * inv);
  }

  // P rows are wave-private; DS pipe is in-order per wave. Ensure writes complete
  // before the PV ds_reads issue (no block barrier needed).
  asm volatile("s_waitcnt lgkmcnt(0)" ::: "memory");
  __builtin_amdgcn_sched_barrier(0);

  // O = P V : V^T frags already in registers
  floatx4 o0 = zacc, o1 = zacc;
#pragma unroll
  for (int kk = 0; kk < 2; ++kk) {
    bf16x8 ap = *(const bf16x8*)((const u16*)Pl + (wv * 16 + il) * 88 + kk * 32 + ch * 8);
    o0 = __builtin_amdgcn_mfma_f32_16x16x32_bf16(ap, bv0[kk], o0, 0, 0, 0);
    o1 = __builtin_amdgcn_mfma_f32_16x16x32_bf16(ap, bv1[kk], o1, 0, 0, 0);
  }

  int img = w >> 6;
#pragma unroll
  for (int r = 0; r < 4; ++r) {
    int i = wv * 16 + ch * 4 + r;
    int ty = i >> 3, tx = i & 7;
    int y = wy * 8 + ty, xp = wx * 8 + tx;
    float* op = out + ((img * 64 + y) * 64 + xp) * 512 + h * 32;
    op[il] = o0[r];
    op[16 + il] = o1[r];
  }
}

extern "C" void kernel_launch(void* const* d_in, const int* in_sizes, int n_in,
                              void* d_out, int out_size, void* d_ws, size_t ws_size,
                              hipStream_t stream) {
  const float* x      = (const float*)d_in[0];
  const float* qkv_w  = (const float*)d_in[1];
  const float* qkv_b  = (const float*)d_in[2];
  const float* btab   = (const float*)d_in[3];
  float* out = (float*)d_out;

  char* ws = (char*)d_ws;
  u16* Wb    = (u16*)ws;                                   // 1.5 MB
  u16* QKV   = (u16*)(ws + (size_t)NQKV * KDIM * 2);       // 96 MB (Q|K|V sections)
  float* tbl = (float*)(ws + (size_t)NQKV * KDIM * 2 + 3 * (size_t)SECSZ * 2);  // 1 MB

  convert_w_tbl<<<dim3(832), dim3(256), 0, stream>>>(qkv_w, btab, Wb, tbl);
  gemm_qkv<<<dim3(3072), dim3(256), 0, stream>>>(x, Wb, qkv_b, QKV);
  attn<<<dim3(NWIN * N_HEAD), dim3(256), 0, stream>>>(QKV, tbl, out);
}

// Round 7
// 216.478 us; speedup vs baseline: 1.1132x; 1.1132x over previous
//
#include <hip/hip_runtime.h>
#include <stdint.h>

typedef unsigned short u16;
typedef __attribute__((ext_vector_type(4))) float floatx4;
typedef __attribute__((ext_vector_type(8))) short bf16x8;

#define MTOK   32768   // 512 windows * 64 tokens
#define KDIM   512
#define NQKV   1536
#define NWIN   512
#define N_HEAD 16
#define SECSZ  (512 * 16 * 2048)   // u16 elems per Q/K/V section (32 MB)
#define QK_SCALE 0.17677669529663687f  // 32^-0.5

__device__ __forceinline__ u16 f2bf(float f) {
  union { float f; unsigned u; } v; v.f = f;
  unsigned r = v.u + 0x7fffu + ((v.u >> 16) & 1u);
  return (u16)(r >> 16);
}

__device__ __forceinline__ void load_lds16(const void* g, void* l) {
  __builtin_amdgcn_global_load_lds((const __attribute__((address_space(1))) void*)g,
                                   (__attribute__((address_space(3))) void*)l,
                                   16, 0, 0);
}

// ---------------- kernel 1: fused converts + bias/mask table gen (R2 form,
// measured ~26 us). The x->A bf16 pre-convert stays a separate pass: fusing it
// into gemm's staging was measured twice (R3 serial, R6 pipelined) at +30..+41 us
// — the 2-phase loop cannot hide fp32 load latency or the convert VALU.
__global__ __launch_bounds__(256) void convert_xw(const float* __restrict__ x,
                                                  const float* __restrict__ wsrc,
                                                  const float* __restrict__ btab,
                                                  u16* __restrict__ A,
                                                  u16* __restrict__ Wb,
                                                  float* __restrict__ tbl) {
  int b = blockIdx.x;
  if (b < 768) {
    int e = (b * 256 + threadIdx.x) * 4;
    const float4 v = *(const float4*)(wsrc + e);
    ushort4 o;
    o.x = f2bf(v.x); o.y = f2bf(v.y); o.z = f2bf(v.z); o.w = f2bf(v.w);
    *(ushort4*)(Wb + e) = o;
  } else if (b < 17152) {
    int idx = (b - 768) * 256 + threadIdx.x;
    int e = idx * 4;
    int c = e & 511;
    int tg = e >> 9;
    int w = tg >> 6, t = tg & 63;
    int img = w >> 6, wy = (w >> 3) & 7, wx = w & 7;
    int ty = t >> 3, tx = t & 7;
    int y = wy * 8 + ty, xp = wx * 8 + tx;
    const float4 v = *(const float4*)(x + (((img * 64 + y) * 64 + xp) * 512 + c));
    ushort4 o;
    o.x = f2bf(v.x); o.y = f2bf(v.y); o.z = f2bf(v.z); o.w = f2bf(v.w);
    *(ushort4*)(A + e) = o;
  } else {
    int q = b - 17152;                 // [0,64): cls*16 + head
    int cls = q >> 4, hh = q & 15;
    int ey = cls >> 1, ex = cls & 1;   // edge flags: wy==7 / wx==7
    float* To = tbl + (q << 12);
#pragma unroll
    for (int e = 0; e < 16; ++e) {
      int idx = e * 256 + threadIdx.x;
      int i = idx >> 6, j = idx & 63;
      int ty = i >> 3, tx = i & 7, sy = j >> 3, sx = j & 7;
      int ry = ey ? (ty < 4 ? 1 : 2) : 0;
      int rx = ex ? (tx < 4 ? 1 : 2) : 0;
      int qy = ey ? (sy < 4 ? 1 : 2) : 0;
      int qx = ex ? (sx < 4 ? 1 : 2) : 0;
      float v = btab[((ty - sy + 7) * 15 + (tx - sx + 7)) * 16 + hh];
      if (ry * 3 + rx != qy * 3 + qx) v -= 100.0f;
      To[idx] = v;
    }
  }
}

// ---------------- kernel 2: QKV GEMM — R0 structure with BK=64.
// Theory: per-K-step the block stalls ~500-900 cy at the post-DMA barrier while
// compute is only ~200 cy (MfmaUtil 28%). BK=64 halves the number of stalls and
// doubles compute per phase (32 MFMA) -> co-resident blocks cover the drain.
// Implementation is layout-preserving: BK=64 = two adjacent 32-wide slices, each
// stored in the byte-identical R0 layout at +8KB offsets; frag reads / MFMA /
// staging swizzle / epilogue untouched. LDS 32KB x 4 blocks/CU = 128 <= 160KB.
__global__ __launch_bounds__(256, 4) void gemm_qkv(const u16* __restrict__ A,
                                                   const u16* __restrict__ Wb,
                                                   const float* __restrict__ bias,
                                                   u16* __restrict__ QKV) {
  __shared__ __attribute__((aligned(16))) char smem[32768];
  u16* Ct = (u16*)smem;

  int b = blockIdx.x;
  int xcd = b & 7, slot = b >> 3;
  int mtile = (slot / 12) * 8 + xcd;   // [0,256)
  int ntile = slot % 12;               // [0,12)

  int tid = threadIdx.x;
  int wv = tid >> 6, lane = tid & 63;
  int il = lane & 15, ch = lane >> 4;
  int wm = (wv & 1) * 64, wn = (wv >> 1) * 64;

  floatx4 acc[4][4];
  floatx4 zacc = {0.f, 0.f, 0.f, 0.f};
#pragma unroll
  for (int m = 0; m < 4; ++m)
#pragma unroll
    for (int n = 0; n < 4; ++n) acc[m][n] = zacc;

  int row0 = tid >> 2;
  int ch4 = (tid & 3) ^ (row0 & 3);    // staging swizzle (R0 form)
  const u16* Abase = A + (mtile * 128 + row0) * KDIM + ch4 * 8;
  const u16* Bbase = Wb + (ntile * 128 + row0) * KDIM + ch4 * 8;
  // smem map: A slice0 [0,8K) A slice1 [8K,16K) B slice0 [16K,24K) B slice1 [24K,32K)
  char* lAb = smem;
  char* lBb = smem + 16384;
  char* lA0s0 = lAb + wv * 1024;
  char* lA1s0 = lAb + 4096 + wv * 1024;
  char* lA0s1 = lAb + 8192 + wv * 1024;
  char* lA1s1 = lAb + 12288 + wv * 1024;
  char* lB0s0 = lBb + wv * 1024;
  char* lB1s0 = lBb + 4096 + wv * 1024;
  char* lB0s1 = lBb + 8192 + wv * 1024;
  char* lB1s1 = lBb + 12288 + wv * 1024;

  int sw = il & 3;
  for (int kb = 0; kb < KDIM; kb += 64) {
    __syncthreads();
    load_lds16(Abase + kb, lA0s0);
    load_lds16(Abase + kb + 64 * KDIM, lA1s0);
    load_lds16(Abase + kb + 32, lA0s1);
    load_lds16(Abase + kb + 32 + 64 * KDIM, lA1s1);
    load_lds16(Bbase + kb, lB0s0);
    load_lds16(Bbase + kb + 64 * KDIM, lB1s0);
    load_lds16(Bbase + kb + 32, lB0s1);
    load_lds16(Bbase + kb + 32 + 64 * KDIM, lB1s1);
    __syncthreads();

#pragma unroll
    for (int s = 0; s < 2; ++s) {
      const char* aB = lAb + s * 8192;
      const char* bB = lBb + s * 8192;
      bf16x8 af[4], bfr[4];
#pragma unroll
      for (int mt = 0; mt < 4; ++mt)
        af[mt] = *(const bf16x8*)(aB + (wm + mt * 16 + il) * 64 + (ch ^ sw) * 16);
#pragma unroll
      for (int nt = 0; nt < 4; ++nt)
        bfr[nt] = *(const bf16x8*)(bB + (wn + nt * 16 + il) * 64 + (ch ^ sw) * 16);
#pragma unroll
      for (int mt = 0; mt < 4; ++mt)
#pragma unroll
        for (int nt = 0; nt < 4; ++nt)
          acc[mt][nt] = __builtin_amdgcn_mfma_f32_16x16x32_bf16(af[mt], bfr[nt], acc[mt][nt], 0, 0, 0);
    }
  }

  __syncthreads();   // K-loop LDS reads done before smem reuse

  // epilogue: C/D layout col=lane&15, row=(lane>>4)*4+reg  (R0, unchanged)
  int sec = ntile >> 2;              // 0=Q 1=K 2=V
  int h0 = (ntile & 3) * 4;          // 4 heads per block
  int gw0 = mtile * 2;               // 2 windows per block
  u16* dst = QKV + (size_t)sec * SECSZ;
  float sc = (sec == 0) ? QK_SCALE : 1.0f;

  for (int p = 0; p < 2; ++p) {      // pass p == window gw0+p (tokens p*64..p*64+63)
    if ((wv & 1) == p) {
      if (sec < 2) {
        // Ct[t_local=64][c=128], row stride 136 u16 (272B, 16*17 aligned)
#pragma unroll
        for (int nt = 0; nt < 4; ++nt) {
          float bv = bias[ntile * 128 + wn + nt * 16 + il];
          int cl = wn + nt * 16 + il;
#pragma unroll
          for (int mt = 0; mt < 4; ++mt) {
            int lr = mt * 16 + ch * 4;
#pragma unroll
            for (int r = 0; r < 4; ++r)
              Ct[(lr + r) * 136 + cl] = f2bf((acc[mt][nt][r] + bv) * sc);
          }
        }
      } else {
        // V transposed: Ct[c=128][t_local=64], row stride 72 u16 (144B, 16*9 aligned)
#pragma unroll
        for (int nt = 0; nt < 4; ++nt) {
          float bv = bias[ntile * 128 + wn + nt * 16 + il];
          int cl = wn + nt * 16 + il;
#pragma unroll
          for (int mt = 0; mt < 4; ++mt) {
            int lr = mt * 16 + ch * 4;
            ushort4 pk;
            pk.x = f2bf(acc[mt][nt][0] + bv);
            pk.y = f2bf(acc[mt][nt][1] + bv);
            pk.z = f2bf(acc[mt][nt][2] + bv);
            pk.w = f2bf(acc[mt][nt][3] + bv);
            *(ushort4*)(Ct + cl * 72 + lr) = pk;
          }
        }
      }
    }
    __syncthreads();

    if (sec < 2) {
      int tl = tid >> 2, dc = tid & 3;
#pragma unroll
      for (int hl = 0; hl < 4; ++hl) {
        uint4 v = *(const uint4*)(smem + tl * 272 + hl * 64 + dc * 16);
        *(uint4*)(dst + ((gw0 + p) * 16 + h0 + hl) * 2048 + tl * 32 + dc * 8) = v;
      }
    } else {
      int c0 = tid >> 3, tq = tid & 7;   // c0: d in [0,32), tq: t-chunk
#pragma unroll
      for (int hl = 0; hl < 4; ++hl) {
        uint4 v = *(const uint4*)(smem + (hl * 32 + c0) * 144 + tq * 16);
        *(uint4*)(dst + ((gw0 + p) * 16 + h0 + hl) * 2048 + c0 * 64 + tq * 8) = v;
      }
    }
    __syncthreads();   // buffer free for next pass's writers
  }
}

// ---------------- kernel 3: attention — R5 version, measured 40.9 us
// (one block per (window,head), 8192 blocks; barrier-free P hand-off within the
// wave; V frags hoisted above softmax). Unchanged.
__global__ __launch_bounds__(256) void attn(const u16* __restrict__ QKV,
                                            const float* __restrict__ tbl,
                                            float* __restrict__ out) {
  __shared__ __attribute__((aligned(16))) u16 Pl[64 * 88];

  int bid = blockIdx.x;
  int w = bid >> 4, h = bid & 15;
  int tid = threadIdx.x;

  int lane = tid & 63, wv = tid >> 6;
  int il = lane & 15, ch = lane >> 4;
  const u16* Qb = QKV + (w * 16 + h) * 2048;
  const u16* Kb = Qb + SECSZ;
  const u16* Vt = Qb + 2 * (size_t)SECSZ;

  bf16x8 aq = *(const bf16x8*)(Qb + (wv * 16 + il) * 32 + ch * 8);
  floatx4 zacc = {0.f, 0.f, 0.f, 0.f};
  floatx4 s[4];
#pragma unroll
  for (int jt = 0; jt < 4; ++jt) {
    bf16x8 bk = *(const bf16x8*)(Kb + (jt * 16 + il) * 32 + ch * 8);
    s[jt] = __builtin_amdgcn_mfma_f32_16x16x32_bf16(aq, bk, zacc, 0, 0, 0);
  }

  // V frags hoisted: issue now, consumed after softmax
  bf16x8 bv0[2], bv1[2];
#pragma unroll
  for (int kk = 0; kk < 2; ++kk) {
    bv0[kk] = *(const bf16x8*)(Vt + il * 64 + kk * 32 + ch * 8);
    bv1[kk] = *(const bf16x8*)(Vt + (16 + il) * 64 + kk * 32 + ch * 8);
  }

  int winidx = w & 63;
  int wy = winidx >> 3, wx = winidx & 7;
  int cls = ((wy == 7) ? 2 : 0) | ((wx == 7) ? 1 : 0);
  const float* T = tbl + (((cls << 4) | h) << 12);

  float val[4][4];
#pragma unroll
  for (int r = 0; r < 4; ++r) {
    int i = wv * 16 + ch * 4 + r;
#pragma unroll
    for (int jt = 0; jt < 4; ++jt)
      val[r][jt] = s[jt][r] + T[i * 64 + jt * 16 + il];
  }

#pragma unroll
  for (int r = 0; r < 4; ++r) {
    float m = fmaxf(fmaxf(val[r][0], val[r][1]), fmaxf(val[r][2], val[r][3]));
    m = fmaxf(m, __shfl_xor(m, 1, 64));
    m = fmaxf(m, __shfl_xor(m, 2, 64));
    m = fmaxf(m, __shfl_xor(m, 4, 64));
    m = fmaxf(m, __shfl_xor(m, 8, 64));
    float sum = 0.f;
#pragma unroll
    for (int jt = 0; jt < 4; ++jt) { val[r][jt] = __expf(val[r][jt] - m); sum += val[r][jt]; }
    sum += __shfl_xor(sum, 1, 64);
    sum += __shfl_xor(sum, 2, 64);
    sum += __shfl_xor(sum, 4, 64);
    sum += __shfl_xor(sum, 8, 64);
    float inv = 1.0f / sum;
    int i = wv * 16 + ch * 4 + r;
#pragma unroll
    for (int jt = 0; jt < 4; ++jt)
      Pl[i * 88 + jt * 16 + il] = f2bf(val[r][jt] * inv);
  }

  // P rows are wave-private; DS pipe is in-order per wave. Ensure writes complete
  // before the PV ds_reads issue (no block barrier needed).
  asm volatile("s_waitcnt lgkmcnt(0)" ::: "memory");
  __builtin_amdgcn_sched_barrier(0);

  // O = P V : V^T frags already in registers
  floatx4 o0 = zacc, o1 = zacc;
#pragma unroll
  for (int kk = 0; kk < 2; ++kk) {
    bf16x8 ap = *(const bf16x8*)((const u16*)Pl + (wv * 16 + il) * 88 + kk * 32 + ch * 8);
    o0 = __builtin_amdgcn_mfma_f32_16x16x32_bf16(ap, bv0[kk], o0, 0, 0, 0);
    o1 = __builtin_amdgcn_mfma_f32_16x16x32_bf16(ap, bv1[kk], o1, 0, 0, 0);
  }

  int img = w >> 6;
#pragma unroll
  for (int r = 0; r < 4; ++r) {
    int i = wv * 16 + ch * 4 + r;
    int ty = i >> 3, tx = i & 7;
    int y = wy * 8 + ty, xp = wx * 8 + tx;
    float* op = out + ((img * 64 + y) * 64 + xp) * 512 + h * 32;
    op[il] = o0[r];
    op[16 + il] = o1[r];
  }
}

extern "C" void kernel_launch(void* const* d_in, const int* in_sizes, int n_in,
                              void* d_out, int out_size, void* d_ws, size_t ws_size,
                              hipStream_t stream) {
  const float* x      = (const float*)d_in[0];
  const float* qkv_w  = (const float*)d_in[1];
  const float* qkv_b  = (const float*)d_in[2];
  const float* btab   = (const float*)d_in[3];
  float* out = (float*)d_out;

  char* ws = (char*)d_ws;
  u16* A    = (u16*)ws;                                              // 32 MB
  u16* Wb   = (u16*)(ws + (size_t)MTOK * KDIM * 2);                  // 1.5 MB
  u16* QKV  = (u16*)(ws + (size_t)MTOK * KDIM * 2 + (size_t)NQKV * KDIM * 2);  // 96 MB
  float* tbl = (float*)(ws + (size_t)MTOK * KDIM * 2 + (size_t)NQKV * KDIM * 2
                           + 3 * (size_t)SECSZ * 2);                 // 1 MB

  convert_xw<<<dim3(17216), dim3(256), 0, stream>>>(x, qkv_w, btab, A, Wb, tbl);
  gemm_qkv<<<dim3(3072), dim3(256), 0, stream>>>(A, Wb, qkv_b, QKV);
  attn<<<dim3(NWIN * N_HEAD), dim3(256), 0, stream>>>(QKV, tbl, out);
}